// Round 1
// baseline (671.404 us; speedup 1.0000x reference)
//
#include <hip/hip_runtime.h>
#include <hip/hip_bf16.h>

// Problem constants
constexpr int BB   = 16;
constexpr int TT_  = 392;          // T
constexpr int CC   = 512;          // C (= E)
constexpr int E8_  = 64;           // E/8
constexpr int KK   = 196;          // top_k
constexpr long TT2 = 153664;       // T*T
constexpr int MROWS = 6272;        // B*T
constexpr int NCHUNK = 49;         // i-chunks in k_xt
constexpr int CHUNK  = 3136;       // i per chunk (49*3136 = 153664)
constexpr long OUT_HALF = 1229312; // B*T*K

// ---------------------------------------------------------------- xi = x @ W_dim^T + b_dim
__global__ __launch_bounds__(256) void k_xi(const float* __restrict__ x,
                                            const float* __restrict__ Wd,
                                            const float* __restrict__ bd,
                                            float* __restrict__ xi) {
    int tid = threadIdx.x;
    int e = tid & 63;
    int m = blockIdx.x * 4 + (tid >> 6);          // 1568 blocks * 4 = 6272
    const float4* xr = (const float4*)(x + (size_t)m * CC);
    const float4* wr = (const float4*)(Wd + (size_t)e * CC);
    float acc = bd[e];
    #pragma unroll 4
    for (int q = 0; q < CC / 4; ++q) {
        float4 a = xr[q], w = wr[q];
        acc += a.x * w.x + a.y * w.y + a.z * w.z + a.w * w.w;
    }
    xi[(size_t)m * E8_ + e] = acc;
}

// ---------------------------------------------------------------- scores = (xi xi^T)/512 per batch
__global__ __launch_bounds__(256) void k_scores(const float* __restrict__ xi,
                                                float* __restrict__ att) {
    __shared__ float As[64][65];
    __shared__ float Bs[64][65];
    int b = blockIdx.x, i0 = blockIdx.y * 64, j0 = blockIdx.z * 64;
    int tid = threadIdx.x;
    const float* xb = xi + (size_t)b * (TT_ * E8_);
    #pragma unroll
    for (int r = 0; r < 16; ++r) {
        int idx = r * 256 + tid;
        int row = idx >> 6, col = idx & 63;
        As[row][col] = (i0 + row < TT_) ? xb[(i0 + row) * E8_ + col] : 0.f;
        Bs[row][col] = (j0 + row < TT_) ? xb[(j0 + row) * E8_ + col] : 0.f;
    }
    __syncthreads();
    int ty = tid >> 4, tx = tid & 15;
    float acc[4][4] = {};
    for (int k = 0; k < 64; ++k) {
        float a0 = As[ty * 4 + 0][k], a1 = As[ty * 4 + 1][k];
        float a2 = As[ty * 4 + 2][k], a3 = As[ty * 4 + 3][k];
        float b0 = Bs[tx * 4 + 0][k], b1 = Bs[tx * 4 + 1][k];
        float b2 = Bs[tx * 4 + 2][k], b3 = Bs[tx * 4 + 3][k];
        acc[0][0] += a0 * b0; acc[0][1] += a0 * b1; acc[0][2] += a0 * b2; acc[0][3] += a0 * b3;
        acc[1][0] += a1 * b0; acc[1][1] += a1 * b1; acc[1][2] += a1 * b2; acc[1][3] += a1 * b3;
        acc[2][0] += a2 * b0; acc[2][1] += a2 * b1; acc[2][2] += a2 * b2; acc[2][3] += a2 * b3;
        acc[3][0] += a3 * b0; acc[3][1] += a3 * b1; acc[3][2] += a3 * b2; acc[3][3] += a3 * b3;
    }
    float* ab = att + (size_t)b * TT2;
    const float scaler = 1.0f / 512.0f;
    #pragma unroll
    for (int r = 0; r < 4; ++r)
        #pragma unroll
        for (int c = 0; c < 4; ++c) {
            int gi = i0 + ty * 4 + r, gj = j0 + tx * 4 + c;
            if (gi < TT_ && gj < TT_) ab[(size_t)gi * TT_ + gj] = acc[r][c] * scaler;
        }
}

// ---------------------------------------------------------------- row softmax (in place), 1 wave/row
__global__ __launch_bounds__(256) void k_softmax(float* __restrict__ att) {
    int row = blockIdx.x * 4 + (threadIdx.x >> 6);   // 1568 blocks * 4 waves
    int lane = threadIdx.x & 63;
    float* p = att + (size_t)row * TT_;
    float v[7];
    float mx = -1e30f;
    #pragma unroll
    for (int s = 0; s < 7; ++s) {
        int j = lane + s * 64;
        v[s] = (j < TT_) ? p[j] : -1e30f;
        mx = fmaxf(mx, v[s]);
    }
    #pragma unroll
    for (int o = 32; o > 0; o >>= 1) mx = fmaxf(mx, __shfl_xor(mx, o, 64));
    float sum = 0.f;
    #pragma unroll
    for (int s = 0; s < 7; ++s) {
        int j = lane + s * 64;
        if (j < TT_) { v[s] = expf(v[s] - mx); sum += v[s]; }
    }
    #pragma unroll
    for (int o = 32; o > 0; o >>= 1) sum += __shfl_xor(sum, o, 64);
    float inv = 1.0f / sum;
    #pragma unroll
    for (int s = 0; s < 7; ++s) {
        int j = lane + s * 64;
        if (j < TT_) p[j] = v[s] * inv;
    }
}

// ---------------------------------------------------------------- xt partials: part[c][j][b]
// grid (49 chunks, 49 j-tiles), block 256 = 8 j x 4 bq x 8 istride
__global__ __launch_bounds__(256) void k_xt(const float* __restrict__ Wt,
                                            const float* __restrict__ att,
                                            float* __restrict__ part) {
    int c = blockIdx.x, n = blockIdx.y;
    int tid = threadIdx.x;
    int jl = tid >> 5;            // 0..7
    int bq = (tid >> 3) & 3;      // 0..3
    int is = tid & 7;             // 0..7
    int j = n * 8 + jl;           // 0..391
    long ibase = (long)c * CHUNK + is * 4;
    const float4* __restrict__ wp = (const float4*)(Wt + (size_t)j * TT2 + ibase);
    const float4* __restrict__ a0 = (const float4*)(att + (size_t)(bq * 4 + 0) * TT2 + ibase);
    const float4* __restrict__ a1 = (const float4*)(att + (size_t)(bq * 4 + 1) * TT2 + ibase);
    const float4* __restrict__ a2 = (const float4*)(att + (size_t)(bq * 4 + 2) * TT2 + ibase);
    const float4* __restrict__ a3 = (const float4*)(att + (size_t)(bq * 4 + 3) * TT2 + ibase);
    float4 acc = {0.f, 0.f, 0.f, 0.f};
    #pragma unroll 2
    for (int it = 0; it < CHUNK / 32; ++it) {     // 98 iters, step 32 floats = 8 float4
        float4 w = wp[it * 8];
        float4 x0 = a0[it * 8];
        float4 x1 = a1[it * 8];
        float4 x2 = a2[it * 8];
        float4 x3 = a3[it * 8];
        acc.x += w.x * x0.x + w.y * x0.y + w.z * x0.z + w.w * x0.w;
        acc.y += w.x * x1.x + w.y * x1.y + w.z * x1.z + w.w * x1.w;
        acc.z += w.x * x2.x + w.y * x2.y + w.z * x2.z + w.w * x2.w;
        acc.w += w.x * x3.x + w.y * x3.y + w.z * x3.z + w.w * x3.w;
    }
    __shared__ float red[8][16][9];   // pad to 9: avoids 8-way bank conflict
    red[jl][bq * 4 + 0][is] = acc.x;
    red[jl][bq * 4 + 1][is] = acc.y;
    red[jl][bq * 4 + 2][is] = acc.z;
    red[jl][bq * 4 + 3][is] = acc.w;
    __syncthreads();
    if (tid < 128) {
        int jj = tid >> 4, bb = tid & 15;
        float s = 0.f;
        #pragma unroll
        for (int u = 0; u < 8; ++u) s += red[jj][bb][u];
        part[(size_t)c * MROWS + (size_t)(n * 8 + jj) * 16 + bb] = s;
    }
}

// ---------------------------------------------------------------- xt[b][j] = sum_c part + b_time
__global__ __launch_bounds__(256) void k_reduce_xt(const float* __restrict__ part,
                                                   const float* __restrict__ bt,
                                                   float* __restrict__ xt) {
    int o = blockIdx.x * 256 + threadIdx.x;
    if (o >= MROWS) return;
    int j = o >> 4, bb = o & 15;
    float s = bt[j];
    #pragma unroll 7
    for (int c = 0; c < NCHUNK; ++c) s += part[(size_t)c * MROWS + o];
    xt[(size_t)bb * TT_ + j] = s;
}

// ---------------------------------------------------------------- offsets -> unnormalized sample coord ix
__global__ __launch_bounds__(256) void k_off(const float* __restrict__ xt,
                                             const float* __restrict__ Wa,
                                             const float* __restrict__ Wd,
                                             float* __restrict__ wix) {
    int o = blockIdx.x * 256 + threadIdx.x;
    if (o >= 2 * BB * KK) return;                  // 6272
    int which = o / (BB * KK);                     // 0 = a, 1 = d
    int rem = o - which * (BB * KK);
    int b = rem / KK;
    int k = rem - b * KK;
    const float4* __restrict__ wr = (const float4*)((which ? Wd : Wa) + (size_t)k * TT_);
    const float4* __restrict__ xr = (const float4*)(xt + (size_t)b * TT_);
    float acc = 0.f;
    #pragma unroll 2
    for (int q = 0; q < TT_ / 4; ++q) {
        float4 w = wr[q], x = xr[q];
        acc += w.x * x.x + w.y * x.y + w.z * x.z + w.w * x.w;
    }
    float off = tanhf(acc) * 2.0f;                 // * RECEPTIVE_FIELD
    float idx = (float)(2 * k + which) + off;      // arange(0,t,2) or arange(1,t+1,2)
    float g = 2.0f * idx / 391.0f - 1.0f;          // normalize_grid, denom = t-1
    float ix = ((g + 1.0f) * 512.0f - 1.0f) * 0.5f; // grid_sample unnormalize, c=512
    wix[o] = ix;
}

// ---------------------------------------------------------------- bilinear gather along channels
__global__ __launch_bounds__(256) void k_sample(const float* __restrict__ x,
                                                const float* __restrict__ wix,
                                                float* __restrict__ out) {
    __shared__ float xr[4][512];
    int b = blockIdx.x, t0 = blockIdx.y * 4;
    int tid = threadIdx.x;
    const float* src = x + ((size_t)b * TT_ + t0) * CC;
    #pragma unroll
    for (int s = 0; s < 8; ++s) {
        int idx = s * 256 + tid;
        ((float*)xr)[idx] = src[idx];
    }
    __syncthreads();
    for (int w = tid; w < 2 * 4 * KK; w += 256) {  // 1568 items
        int which = (w >= 4 * KK) ? 1 : 0;
        int rem = w - which * 4 * KK;
        int tl = rem / KK;
        int k = rem - tl * KK;
        float ix = wix[(size_t)which * (BB * KK) + b * KK + k];
        float x0f = floorf(ix);
        float w1 = ix - x0f;
        int c0 = (int)x0f;
        int c1 = c0 + 1;
        c0 = min(max(c0, 0), CC - 1);
        c1 = min(max(c1, 0), CC - 1);
        float v0 = xr[tl][c0], v1 = xr[tl][c1];
        out[(size_t)which * OUT_HALF + ((size_t)(b * TT_) + t0 + tl) * KK + k] =
            v0 * (1.0f - w1) + v1 * w1;
    }
}

extern "C" void kernel_launch(void* const* d_in, const int* in_sizes, int n_in,
                              void* d_out, int out_size, void* d_ws, size_t ws_size,
                              hipStream_t stream) {
    const float* x_in   = (const float*)d_in[0];
    const float* W_dim  = (const float*)d_in[1];
    const float* b_dim  = (const float*)d_in[2];
    const float* W_time = (const float*)d_in[3];
    const float* b_time = (const float*)d_in[4];
    const float* W_offa = (const float*)d_in[5];
    const float* W_offd = (const float*)d_in[6];
    float* out = (float*)d_out;
    float* ws  = (float*)d_ws;

    // ws layout (floats):
    float* att  = ws;                          // 16*153664 = 2,458,624
    float* xi   = ws + 2458624;                // 6272*64   =   401,408
    float* part = xi;                          // reuse xi after k_scores: 49*6272 = 307,328
    float* xt   = ws + 2458624 + 401408;       // 6,272
    float* wix  = xt + 6272;                   // 6,272
    // total ~11.5 MB of ws

    k_xi<<<MROWS / 4, 256, 0, stream>>>(x_in, W_dim, b_dim, xi);
    k_scores<<<dim3(BB, 7, 7), 256, 0, stream>>>(xi, att);
    k_softmax<<<MROWS / 4, 256, 0, stream>>>(att);
    k_xt<<<dim3(NCHUNK, TT_ / 8), 256, 0, stream>>>(W_time, att, part);
    k_reduce_xt<<<25, 256, 0, stream>>>(part, b_time, xt);
    k_off<<<25, 256, 0, stream>>>(xt, W_offa, W_offd, wix);
    k_sample<<<dim3(BB, TT_ / 4), 256, 0, stream>>>(x_in, wix, out);
}

// Round 2
// 441.802 us; speedup vs baseline: 1.5197x; 1.5197x over previous
//
#include <hip/hip_runtime.h>
#include <hip/hip_bf16.h>

// Problem constants
constexpr int BB   = 16;
constexpr int TT_  = 392;          // T
constexpr int CC   = 512;          // C (= E)
constexpr int E8_  = 64;           // E/8
constexpr int KK   = 196;          // top_k
constexpr long TT2 = 153664;       // T*T
constexpr long OUT_HALF = 1229312; // B*T*K

// k_xt tiling
constexpr int NC2   = 98;          // K-chunks
constexpr int CH2   = 1568;        // K per chunk (NC2*CH2 = T*T)
constexpr int BK2   = 224;         // K per LDS stage
constexpr int NSTEP = 7;           // CH2/BK2
constexpr int LDW   = 232;         // padded LDS row stride (bf16 elems), 464B = 29*16 ✓
constexpr int NJT   = 13;          // j-tiles of 32 (13*32=416 >= 392)
constexpr int PJ    = 448;         // padded j extent of partials

typedef __bf16 bf16_t;
typedef bf16_t bf16x8 __attribute__((ext_vector_type(8)));
typedef float  f32x4  __attribute__((ext_vector_type(4)));

static __device__ __forceinline__ unsigned int pk2(float a, float b) {
    unsigned short lo = __builtin_bit_cast(unsigned short, (bf16_t)a);
    unsigned short hi = __builtin_bit_cast(unsigned short, (bf16_t)b);
    return ((unsigned int)hi << 16) | (unsigned int)lo;
}
static __device__ __forceinline__ float bf2f(unsigned short u) {
    unsigned int w = ((unsigned int)u) << 16;
    return __builtin_bit_cast(float, w);
}

// ---------------------------------------------------------------- xi = x @ W_dim^T + b_dim  (MFMA)
// grid 98, block 256 (4 waves). Block tile: 64 m-rows x 64 e. K=512 in 16 steps of 32.
__global__ __launch_bounds__(256) void k_xi(const float* __restrict__ x,
                                            const float* __restrict__ Wd,
                                            const float* __restrict__ bd,
                                            float* __restrict__ xi) {
    __shared__ bf16_t Xl[64 * 40];
    __shared__ bf16_t Wl[64 * 40];
    int m0 = blockIdx.x * 64;
    int tid = threadIdx.x;
    int wv = tid >> 6, lane = tid & 63;
    int n = lane & 15, quad = lane >> 4;
    f32x4 acc[4] = {};
    for (int kt = 0; kt < 16; ++kt) {
        __syncthreads();
        // stage both tiles: 64 rows x 8 float4 each = 512 slots per tile
        #pragma unroll
        for (int t = 0; t < 2; ++t) {
            int s = t * 256 + tid;          // 0..511
            int r = s >> 3, c4 = s & 7;
            f32x4 xv = *(const f32x4*)(x + (size_t)(m0 + r) * CC + kt * 32 + c4 * 4);
            f32x4 wvv = *(const f32x4*)(Wd + (size_t)r * CC + kt * 32 + c4 * 4);
            *(uint2*)(&Xl[r * 40 + c4 * 4]) = make_uint2(pk2(xv.x, xv.y), pk2(xv.z, xv.w));
            *(uint2*)(&Wl[r * 40 + c4 * 4]) = make_uint2(pk2(wvv.x, wvv.y), pk2(wvv.z, wvv.w));
        }
        __syncthreads();
        bf16x8 a = *(const bf16x8*)(&Xl[(wv * 16 + n) * 40 + quad * 8]);
        #pragma unroll
        for (int nt = 0; nt < 4; ++nt) {
            bf16x8 b = *(const bf16x8*)(&Wl[(nt * 16 + n) * 40 + quad * 8]);
            acc[nt] = __builtin_amdgcn_mfma_f32_16x16x32_bf16(a, b, acc[nt], 0, 0, 0);
        }
    }
    #pragma unroll
    for (int nt = 0; nt < 4; ++nt)
        #pragma unroll
        for (int r = 0; r < 4; ++r) {
            int m = m0 + wv * 16 + quad * 4 + r;
            int e = nt * 16 + n;
            xi[(size_t)m * E8_ + e] = acc[nt][r] + bd[e];
        }
}

// ---------------------------------------------------------------- fused scores + softmax -> att bf16
// grid (16 b, 7 ti-tiles), block 256 (4 waves). Wave: 16 ti x full 392 tj (25 n-tiles).
__global__ __launch_bounds__(256) void k_att(const float* __restrict__ xi,
                                             unsigned short* __restrict__ att_b) {
    __shared__ bf16_t Xb[400 * 40];
    int b = blockIdx.x, tb = blockIdx.y;
    int tid = threadIdx.x;
    int wv = tid >> 6, lane = tid & 63;
    int n = lane & 15, quad = lane >> 4;
    // stage xi batch (392x64 fp32 -> bf16), rows 392..399 zero. 400*16 = 6400 uint2 slots.
    #pragma unroll
    for (int t = 0; t < 25; ++t) {
        int s = t * 256 + tid;              // 0..6399
        int r = s >> 4, c4 = s & 15;
        uint2 v = make_uint2(0u, 0u);
        if (r < TT_) {
            f32x4 xv = *(const f32x4*)(xi + (size_t)(b * TT_ + r) * E8_ + c4 * 4);
            v = make_uint2(pk2(xv.x, xv.y), pk2(xv.z, xv.w));
        }
        *(uint2*)(&Xb[r * 40 + c4 * 4]) = v;
    }
    __syncthreads();
    int arow = tb * 64 + wv * 16 + n;
    if (arow > 399) arow = 399;
    bf16x8 a0 = *(const bf16x8*)(&Xb[arow * 40]);
    bf16x8 a1 = *(const bf16x8*)(&Xb[arow * 40 + 32]);
    f32x4 acc[25];
    #pragma unroll
    for (int nt = 0; nt < 25; ++nt) acc[nt] = (f32x4){0.f, 0.f, 0.f, 0.f};
    #pragma unroll
    for (int nt = 0; nt < 25; ++nt) {
        bf16x8 b0 = *(const bf16x8*)(&Xb[(nt * 16 + n) * 40]);
        bf16x8 b1 = *(const bf16x8*)(&Xb[(nt * 16 + n) * 40 + 32]);
        acc[nt] = __builtin_amdgcn_mfma_f32_16x16x32_bf16(a0, b0, acc[nt], 0, 0, 0);
        acc[nt] = __builtin_amdgcn_mfma_f32_16x16x32_bf16(a1, b1, acc[nt], 0, 0, 0);
    }
    // per-lane rows m = quad*4 + r; cols tj = nt*16 + n. Row spans the 16 lanes of the quad.
    const float scaler = 1.0f / 512.0f;
    float mx[4] = {-1e30f, -1e30f, -1e30f, -1e30f};
    #pragma unroll
    for (int nt = 0; nt < 25; ++nt) {
        bool valid = (nt * 16 + n) < TT_;
        #pragma unroll
        for (int r = 0; r < 4; ++r) {
            float v = valid ? acc[nt][r] * scaler : -1e30f;
            acc[nt][r] = v;
            mx[r] = fmaxf(mx[r], v);
        }
    }
    #pragma unroll
    for (int r = 0; r < 4; ++r) {
        #pragma unroll
        for (int o = 1; o < 16; o <<= 1) mx[r] = fmaxf(mx[r], __shfl_xor(mx[r], o, 64));
    }
    float sm[4] = {0.f, 0.f, 0.f, 0.f};
    #pragma unroll
    for (int nt = 0; nt < 25; ++nt)
        #pragma unroll
        for (int r = 0; r < 4; ++r) {
            float e = __expf(acc[nt][r] - mx[r]);
            acc[nt][r] = e;
            sm[r] += e;
        }
    #pragma unroll
    for (int r = 0; r < 4; ++r) {
        #pragma unroll
        for (int o = 1; o < 16; o <<= 1) sm[r] += __shfl_xor(sm[r], o, 64);
        sm[r] = 1.0f / sm[r];
    }
    unsigned short* dst = att_b + (size_t)b * TT2;
    #pragma unroll
    for (int r = 0; r < 4; ++r) {
        int ti = tb * 64 + wv * 16 + quad * 4 + r;
        if (ti < TT_) {
            #pragma unroll
            for (int nt = 0; nt < 25; ++nt) {
                int tj = nt * 16 + n;
                if (tj < TT_)
                    dst[(size_t)ti * TT_ + tj] =
                        __builtin_bit_cast(unsigned short, (bf16_t)(acc[nt][r] * sm[r]));
            }
        }
    }
}

// ---------------------------------------------------------------- xt partials via MFMA
// grid (98 chunks, 13 j-tiles), block 128 (2 waves). Tile: 16 b x 32 j, K = 1568 in 7 stages of 224.
__global__ __launch_bounds__(128) void k_xt(const float* __restrict__ Wt,
                                            const unsigned short* __restrict__ att_b,
                                            unsigned short* __restrict__ part_b) {
    __shared__ bf16_t Wl[32 * LDW];
    __shared__ bf16_t Al[16 * LDW];
    int c = blockIdx.x, jt = blockIdx.y;
    int tid = threadIdx.x;
    int wv = tid >> 6, lane = tid & 63;
    int n = lane & 15, quad = lane >> 4;
    f32x4 acc = {0.f, 0.f, 0.f, 0.f};
    long kbase = (long)c * CH2;
    for (int s = 0; s < NSTEP; ++s) {
        long k0 = kbase + (long)s * BK2;
        __syncthreads();
        // stage W: 32 rows x 56 float4 (896B contiguous per row) -> bf16
        #pragma unroll
        for (int t = 0; t < 14; ++t) {
            int idx = t * 128 + tid;        // 0..1791
            int r = idx / 56, col = idx - r * 56;
            int jg = jt * 32 + r; if (jg > 391) jg = 391;
            f32x4 w = *(const f32x4*)(Wt + (size_t)jg * TT2 + k0 + col * 4);
            *(uint2*)(&Wl[r * LDW + col * 4]) = make_uint2(pk2(w.x, w.y), pk2(w.z, w.w));
        }
        // stage att: 16 rows x 28 x 16B (already bf16)
        #pragma unroll
        for (int t = 0; t < 4; ++t) {
            int idx = t * 128 + tid;        // 0..511, guard 448
            if (idx < 448) {
                int r = idx / 28, q = idx - r * 28;
                uint4 v = *(const uint4*)(att_b + (size_t)r * TT2 + k0 + q * 8);
                *(uint4*)(&Al[r * LDW + q * 8]) = v;
            }
        }
        __syncthreads();
        #pragma unroll
        for (int m = 0; m < 7; ++m) {
            int k = m * 32;
            bf16x8 a = *(const bf16x8*)(&Al[n * LDW + k + quad * 8]);
            bf16x8 b = *(const bf16x8*)(&Wl[(wv * 16 + n) * LDW + k + quad * 8]);
            acc = __builtin_amdgcn_mfma_f32_16x16x32_bf16(a, b, acc, 0, 0, 0);
        }
    }
    int j = jt * 32 + wv * 16 + n;          // < 416 < PJ
    #pragma unroll
    for (int r = 0; r < 4; ++r) {
        int m = quad * 4 + r;               // batch index
        part_b[(size_t)c * (16 * PJ) + (size_t)m * PJ + j] =
            __builtin_bit_cast(unsigned short, (bf16_t)acc[r]);
    }
}

// ---------------------------------------------------------------- xt[b][j] = sum_c part + b_time
__global__ __launch_bounds__(256) void k_reduce_xt(const unsigned short* __restrict__ part_b,
                                                   const float* __restrict__ bt,
                                                   float* __restrict__ xt) {
    int o = blockIdx.x * 256 + threadIdx.x;
    if (o >= 16 * 56) return;               // 16 b x 56 col8
    int b = o / 56, c8 = o - b * 56;
    float s[8] = {};
    for (int c = 0; c < NC2; ++c) {
        uint4 v = *(const uint4*)(part_b + (size_t)c * (16 * PJ) + (size_t)b * PJ + c8 * 8);
        unsigned int w[4] = {v.x, v.y, v.z, v.w};
        #pragma unroll
        for (int t = 0; t < 4; ++t) {
            s[t * 2 + 0] += bf2f((unsigned short)(w[t] & 0xffffu));
            s[t * 2 + 1] += bf2f((unsigned short)(w[t] >> 16));
        }
    }
    #pragma unroll
    for (int t = 0; t < 8; ++t) {
        int j = c8 * 8 + t;
        if (j < TT_) xt[(size_t)b * TT_ + j] = s[t] + bt[j];
    }
}

// ---------------------------------------------------------------- offsets -> unnormalized sample coord ix
__global__ __launch_bounds__(256) void k_off(const float* __restrict__ xt,
                                             const float* __restrict__ Wa,
                                             const float* __restrict__ Wd,
                                             float* __restrict__ wix) {
    int o = blockIdx.x * 256 + threadIdx.x;
    if (o >= 2 * BB * KK) return;                  // 6272
    int which = o / (BB * KK);                     // 0 = a, 1 = d
    int rem = o - which * (BB * KK);
    int b = rem / KK;
    int k = rem - b * KK;
    const f32x4* __restrict__ wr = (const f32x4*)((which ? Wd : Wa) + (size_t)k * TT_);
    const f32x4* __restrict__ xr = (const f32x4*)(xt + (size_t)b * TT_);
    float acc = 0.f;
    #pragma unroll 2
    for (int q = 0; q < TT_ / 4; ++q) {
        f32x4 w = wr[q], x = xr[q];
        acc += w.x * x.x + w.y * x.y + w.z * x.z + w.w * x.w;
    }
    float off = tanhf(acc) * 2.0f;                 // * RECEPTIVE_FIELD
    float idx = (float)(2 * k + which) + off;      // arange(0,t,2) or arange(1,t+1,2)
    float g = 2.0f * idx / 391.0f - 1.0f;          // normalize_grid, denom = t-1
    float ix = ((g + 1.0f) * 512.0f - 1.0f) * 0.5f; // grid_sample unnormalize, c=512
    wix[o] = ix;
}

// ---------------------------------------------------------------- bilinear gather along channels
__global__ __launch_bounds__(256) void k_sample(const float* __restrict__ x,
                                                const float* __restrict__ wix,
                                                float* __restrict__ out) {
    __shared__ float xr[4][512];
    int b = blockIdx.x, t0 = blockIdx.y * 4;
    int tid = threadIdx.x;
    const float* src = x + ((size_t)b * TT_ + t0) * CC;
    #pragma unroll
    for (int s = 0; s < 8; ++s) {
        int idx = s * 256 + tid;
        ((float*)xr)[idx] = src[idx];
    }
    __syncthreads();
    for (int w = tid; w < 2 * 4 * KK; w += 256) {  // 1568 items
        int which = (w >= 4 * KK) ? 1 : 0;
        int rem = w - which * 4 * KK;
        int tl = rem / KK;
        int k = rem - tl * KK;
        float ix = wix[(size_t)which * (BB * KK) + b * KK + k];
        float x0f = floorf(ix);
        float w1 = ix - x0f;
        int c0 = (int)x0f;
        int c1 = c0 + 1;
        c0 = min(max(c0, 0), CC - 1);
        c1 = min(max(c1, 0), CC - 1);
        float v0 = xr[tl][c0], v1 = xr[tl][c1];
        out[(size_t)which * OUT_HALF + ((size_t)(b * TT_) + t0 + tl) * KK + k] =
            v0 * (1.0f - w1) + v1 * w1;
    }
}

extern "C" void kernel_launch(void* const* d_in, const int* in_sizes, int n_in,
                              void* d_out, int out_size, void* d_ws, size_t ws_size,
                              hipStream_t stream) {
    const float* x_in   = (const float*)d_in[0];
    const float* W_dim  = (const float*)d_in[1];
    const float* b_dim  = (const float*)d_in[2];
    const float* W_time = (const float*)d_in[3];
    const float* b_time = (const float*)d_in[4];
    const float* W_offa = (const float*)d_in[5];
    const float* W_offd = (const float*)d_in[6];
    float* out = (float*)d_out;
    float* ws  = (float*)d_ws;

    // ws layout (float units):
    unsigned short* att_b  = (unsigned short*)ws;            // 16*153664 bf16 = 1,229,312 fl
    float*          xi     = ws + 1229312;                   // 6272*64 fp32   =   401,408 fl
    unsigned short* part_b = (unsigned short*)(ws + 1630720);// 98*16*448 bf16 =   351,232 fl
    float*          xt     = ws + 1981952;                   //     6,272 fl
    float*          wix    = ws + 1988224;                   //     6,272 fl
    // total ~8.0 MB

    k_xi<<<98, 256, 0, stream>>>(x_in, W_dim, b_dim, xi);
    k_att<<<dim3(BB, 7), 256, 0, stream>>>(xi, att_b);
    k_xt<<<dim3(NC2, NJT), 128, 0, stream>>>(W_time, att_b, part_b);
    k_reduce_xt<<<4, 256, 0, stream>>>(part_b, b_time, xt);
    k_off<<<25, 256, 0, stream>>>(xt, W_offa, W_offd, wix);
    k_sample<<<dim3(BB, TT_ / 4), 256, 0, stream>>>(x_in, wix, out);
}

// Round 3
// 406.975 us; speedup vs baseline: 1.6497x; 1.0856x over previous
//
#include <hip/hip_runtime.h>
#include <hip/hip_bf16.h>

// Problem constants
constexpr int BB   = 16;
constexpr int TT_  = 392;          // T
constexpr int CC   = 512;          // C (= E)
constexpr int E8_  = 64;           // E/8
constexpr int KK   = 196;          // top_k
constexpr long TT2 = 153664;       // T*T
constexpr long OUT_HALF = 1229312; // B*T*K

// k_xt tiling
constexpr int NC2   = 98;          // K-chunks
constexpr int CH2   = 1568;        // K per chunk (NC2*CH2 = T*T)
constexpr int BK2   = 224;         // K per LDS stage
constexpr int NSTEP = 7;           // CH2/BK2
constexpr int NJT   = 13;          // j-tiles of 32 (13*32=416 >= 392)
// LDS row strides in bf16 elems. Chosen so byte-stride ≡ 8 (mod 16):
// dword-stride ≡ 2 (mod 4) -> 16 n-lanes hit 16 distinct banks (2-way = free).
constexpr int LDW = 228;           // k_xt rows (224 elems + pad)
constexpr int LDX = 36;            // k_xi rows (32 elems + pad)
constexpr int LDA = 68;            // k_att rows (64 elems + pad)

typedef __bf16 bf16_t;
typedef bf16_t bf16x8 __attribute__((ext_vector_type(8)));
typedef float  f32x4  __attribute__((ext_vector_type(4)));

static __device__ __forceinline__ unsigned int pk2(float a, float b) {
    unsigned short lo = __builtin_bit_cast(unsigned short, (bf16_t)a);
    unsigned short hi = __builtin_bit_cast(unsigned short, (bf16_t)b);
    return ((unsigned int)hi << 16) | (unsigned int)lo;
}
// 8B-aligned fragment load: two ds_read_b64 (rows are 8-mod-16 aligned by design)
static __device__ __forceinline__ bf16x8 ld_frag(const bf16_t* p) {
    uint2 lo = *(const uint2*)p;
    uint2 hi = *(const uint2*)(p + 4);
    uint4 u = make_uint4(lo.x, lo.y, hi.x, hi.y);
    return __builtin_bit_cast(bf16x8, u);
}

// ---------------------------------------------------------------- xi = x @ W_dim^T + b_dim  (MFMA)
// grid 98, block 256 (4 waves). Block tile: 64 m-rows x 64 e. K=512 in 16 steps of 32.
// Also zero-inits xt (ws is poisoned 0xAA every call).
__global__ __launch_bounds__(256) void k_xi(const float* __restrict__ x,
                                            const float* __restrict__ Wd,
                                            const float* __restrict__ bd,
                                            float* __restrict__ xi,
                                            float* __restrict__ xt) {
    __shared__ bf16_t Xl[64 * LDX];
    __shared__ bf16_t Wl[64 * LDX];
    int tid = threadIdx.x;
    if (blockIdx.x < 25) {
        int o = blockIdx.x * 256 + tid;
        if (o < BB * TT_) xt[o] = 0.f;
    }
    int m0 = blockIdx.x * 64;
    int wv = tid >> 6, lane = tid & 63;
    int n = lane & 15, quad = lane >> 4;
    f32x4 acc[4] = {};
    for (int kt = 0; kt < 16; ++kt) {
        __syncthreads();
        #pragma unroll
        for (int t = 0; t < 2; ++t) {
            int s = t * 256 + tid;          // 0..511
            int r = s >> 3, c4 = s & 7;
            f32x4 xv = *(const f32x4*)(x + (size_t)(m0 + r) * CC + kt * 32 + c4 * 4);
            f32x4 wq = *(const f32x4*)(Wd + (size_t)r * CC + kt * 32 + c4 * 4);
            *(uint2*)(&Xl[r * LDX + c4 * 4]) = make_uint2(pk2(xv.x, xv.y), pk2(xv.z, xv.w));
            *(uint2*)(&Wl[r * LDX + c4 * 4]) = make_uint2(pk2(wq.x, wq.y), pk2(wq.z, wq.w));
        }
        __syncthreads();
        bf16x8 a = ld_frag(&Xl[(wv * 16 + n) * LDX + quad * 8]);
        #pragma unroll
        for (int nt = 0; nt < 4; ++nt) {
            bf16x8 b = ld_frag(&Wl[(nt * 16 + n) * LDX + quad * 8]);
            acc[nt] = __builtin_amdgcn_mfma_f32_16x16x32_bf16(a, b, acc[nt], 0, 0, 0);
        }
    }
    #pragma unroll
    for (int nt = 0; nt < 4; ++nt)
        #pragma unroll
        for (int r = 0; r < 4; ++r) {
            int m = m0 + wv * 16 + quad * 4 + r;
            int e = nt * 16 + n;
            xi[(size_t)m * E8_ + e] = acc[nt][r] + bd[e];
        }
}

// ---------------------------------------------------------------- fused scores + softmax -> att bf16
// grid (16 b, 7 ti-tiles), block 256 (4 waves). Wave: 16 ti x full 392 tj (25 n-tiles).
__global__ __launch_bounds__(256) void k_att(const float* __restrict__ xi,
                                             unsigned short* __restrict__ att_b) {
    __shared__ bf16_t Xb[400 * LDA];
    int b = blockIdx.x, tb = blockIdx.y;
    int tid = threadIdx.x;
    int wv = tid >> 6, lane = tid & 63;
    int n = lane & 15, quad = lane >> 4;
    // stage xi batch (392x64 fp32 -> bf16), rows 392..399 zero. 400*16 = 6400 uint2 slots.
    #pragma unroll
    for (int t = 0; t < 25; ++t) {
        int s = t * 256 + tid;              // 0..6399
        int r = s >> 4, c4 = s & 15;
        uint2 v = make_uint2(0u, 0u);
        if (r < TT_) {
            f32x4 xv = *(const f32x4*)(xi + (size_t)(b * TT_ + r) * E8_ + c4 * 4);
            v = make_uint2(pk2(xv.x, xv.y), pk2(xv.z, xv.w));
        }
        *(uint2*)(&Xb[r * LDA + c4 * 4]) = v;
    }
    __syncthreads();
    int arow = tb * 64 + wv * 16 + n;
    if (arow > 399) arow = 399;
    bf16x8 a0 = ld_frag(&Xb[arow * LDA + quad * 8]);        // k 0..31
    bf16x8 a1 = ld_frag(&Xb[arow * LDA + 32 + quad * 8]);   // k 32..63
    f32x4 acc[25];
    #pragma unroll
    for (int nt = 0; nt < 25; ++nt) acc[nt] = (f32x4){0.f, 0.f, 0.f, 0.f};
    #pragma unroll
    for (int nt = 0; nt < 25; ++nt) {
        bf16x8 b0 = ld_frag(&Xb[(nt * 16 + n) * LDA + quad * 8]);
        bf16x8 b1 = ld_frag(&Xb[(nt * 16 + n) * LDA + 32 + quad * 8]);
        acc[nt] = __builtin_amdgcn_mfma_f32_16x16x32_bf16(a0, b0, acc[nt], 0, 0, 0);
        acc[nt] = __builtin_amdgcn_mfma_f32_16x16x32_bf16(a1, b1, acc[nt], 0, 0, 0);
    }
    // per-lane rows ti = quad*4 + r (within wave tile); cols tj = nt*16 + n.
    const float scaler = 1.0f / 512.0f;
    float mx[4] = {-1e30f, -1e30f, -1e30f, -1e30f};
    #pragma unroll
    for (int nt = 0; nt < 25; ++nt) {
        bool valid = (nt * 16 + n) < TT_;
        #pragma unroll
        for (int r = 0; r < 4; ++r) {
            float v = valid ? acc[nt][r] * scaler : -1e30f;
            acc[nt][r] = v;
            mx[r] = fmaxf(mx[r], v);
        }
    }
    #pragma unroll
    for (int r = 0; r < 4; ++r) {
        #pragma unroll
        for (int o = 1; o < 16; o <<= 1) mx[r] = fmaxf(mx[r], __shfl_xor(mx[r], o, 64));
    }
    float sm[4] = {0.f, 0.f, 0.f, 0.f};
    #pragma unroll
    for (int nt = 0; nt < 25; ++nt)
        #pragma unroll
        for (int r = 0; r < 4; ++r) {
            float e = __expf(acc[nt][r] - mx[r]);
            acc[nt][r] = e;
            sm[r] += e;
        }
    #pragma unroll
    for (int r = 0; r < 4; ++r) {
        #pragma unroll
        for (int o = 1; o < 16; o <<= 1) sm[r] += __shfl_xor(sm[r], o, 64);
        sm[r] = 1.0f / sm[r];
    }
    unsigned short* dst = att_b + (size_t)b * TT2;
    #pragma unroll
    for (int r = 0; r < 4; ++r) {
        int ti = tb * 64 + wv * 16 + quad * 4 + r;
        if (ti < TT_) {
            #pragma unroll
            for (int nt = 0; nt < 25; ++nt) {
                int tj = nt * 16 + n;
                if (tj < TT_)
                    dst[(size_t)ti * TT_ + tj] =
                        __builtin_bit_cast(unsigned short, (bf16_t)(acc[nt][r] * sm[r]));
            }
        }
    }
}

// ---------------------------------------------------------------- xt via MFMA + fp32 atomic accumulate
// grid (98 chunks, 13 j-tiles), block 128 (2 waves). Tile: 16 b x 32 j, K = 1568 in 7 stages of 224.
__global__ __launch_bounds__(128) void k_xt(const float* __restrict__ Wt,
                                            const unsigned short* __restrict__ att_b,
                                            float* __restrict__ xt) {
    __shared__ bf16_t Wl[32 * LDW];
    __shared__ bf16_t Al[16 * LDW];
    int c = blockIdx.x, jt = blockIdx.y;
    int tid = threadIdx.x;
    int wv = tid >> 6, lane = tid & 63;
    int n = lane & 15, quad = lane >> 4;
    f32x4 acc = {0.f, 0.f, 0.f, 0.f};
    long kbase = (long)c * CH2;
    for (int s = 0; s < NSTEP; ++s) {
        long k0 = kbase + (long)s * BK2;
        __syncthreads();
        // stage W: 32 rows x 56 float4 (896B contiguous per row) -> bf16
        #pragma unroll
        for (int t = 0; t < 14; ++t) {
            int idx = t * 128 + tid;        // 0..1791
            int r = idx / 56, col = idx - r * 56;
            int jg = jt * 32 + r; if (jg > 391) jg = 391;
            f32x4 w = *(const f32x4*)(Wt + (size_t)jg * TT2 + k0 + col * 4);
            *(uint2*)(&Wl[r * LDW + col * 4]) = make_uint2(pk2(w.x, w.y), pk2(w.z, w.w));
        }
        // stage att: 16 rows x 28 x 16B (already bf16); write as 2x8B (rows 8-mod-16 aligned)
        #pragma unroll
        for (int t = 0; t < 4; ++t) {
            int idx = t * 128 + tid;        // 0..511, guard 448
            if (idx < 448) {
                int r = idx / 28, q = idx - r * 28;
                uint4 v = *(const uint4*)(att_b + (size_t)r * TT2 + k0 + q * 8);
                *(uint2*)(&Al[r * LDW + q * 8])     = make_uint2(v.x, v.y);
                *(uint2*)(&Al[r * LDW + q * 8 + 4]) = make_uint2(v.z, v.w);
            }
        }
        __syncthreads();
        #pragma unroll
        for (int m = 0; m < 7; ++m) {
            int k = m * 32;
            bf16x8 a = ld_frag(&Al[n * LDW + k + quad * 8]);
            bf16x8 b = ld_frag(&Wl[(wv * 16 + n) * LDW + k + quad * 8]);
            acc = __builtin_amdgcn_mfma_f32_16x16x32_bf16(a, b, acc, 0, 0, 0);
        }
    }
    int j = jt * 32 + wv * 16 + n;
    if (j < TT_) {
        #pragma unroll
        for (int r = 0; r < 4; ++r) {
            int m = quad * 4 + r;               // batch index
            unsafeAtomicAdd(&xt[(size_t)m * TT_ + j], acc[r]);
        }
    }
}

// ---------------------------------------------------------------- offsets -> unnormalized sample coord ix
// Folds b_time into the dot (xt holds the bias-free sums).
__global__ __launch_bounds__(256) void k_off(const float* __restrict__ xt,
                                             const float* __restrict__ bt,
                                             const float* __restrict__ Wa,
                                             const float* __restrict__ Wd,
                                             float* __restrict__ wix) {
    int o = blockIdx.x * 256 + threadIdx.x;
    if (o >= 2 * BB * KK) return;                  // 6272
    int which = o / (BB * KK);                     // 0 = a, 1 = d
    int rem = o - which * (BB * KK);
    int b = rem / KK;
    int k = rem - b * KK;
    const f32x4* __restrict__ wr = (const f32x4*)((which ? Wd : Wa) + (size_t)k * TT_);
    const f32x4* __restrict__ xr = (const f32x4*)(xt + (size_t)b * TT_);
    const f32x4* __restrict__ br = (const f32x4*)bt;
    float acc = 0.f;
    #pragma unroll 2
    for (int q = 0; q < TT_ / 4; ++q) {
        f32x4 w = wr[q], x = xr[q], bb = br[q];
        acc += (x.x + bb.x) * w.x + (x.y + bb.y) * w.y
             + (x.z + bb.z) * w.z + (x.w + bb.w) * w.w;
    }
    float off = tanhf(acc) * 2.0f;                 // * RECEPTIVE_FIELD
    float idx = (float)(2 * k + which) + off;      // arange(0,t,2) or arange(1,t+1,2)
    float g = 2.0f * idx / 391.0f - 1.0f;          // normalize_grid, denom = t-1
    float ix = ((g + 1.0f) * 512.0f - 1.0f) * 0.5f; // grid_sample unnormalize, c=512
    wix[o] = ix;
}

// ---------------------------------------------------------------- bilinear gather along channels
__global__ __launch_bounds__(256) void k_sample(const float* __restrict__ x,
                                                const float* __restrict__ wix,
                                                float* __restrict__ out) {
    __shared__ float xr[4][512];
    int b = blockIdx.x, t0 = blockIdx.y * 4;
    int tid = threadIdx.x;
    const float* src = x + ((size_t)b * TT_ + t0) * CC;
    #pragma unroll
    for (int s = 0; s < 2; ++s) {
        int idx = s * 256 + tid;                   // 0..511 float4 slots
        ((f32x4*)xr)[idx] = ((const f32x4*)src)[idx];
    }
    __syncthreads();
    for (int w = tid; w < 2 * 4 * KK; w += 256) {  // 1568 items
        int which = (w >= 4 * KK) ? 1 : 0;
        int rem = w - which * 4 * KK;
        int tl = rem / KK;
        int k = rem - tl * KK;
        float ix = wix[(size_t)which * (BB * KK) + b * KK + k];
        float x0f = floorf(ix);
        float w1 = ix - x0f;
        int c0 = (int)x0f;
        int c1 = c0 + 1;
        c0 = min(max(c0, 0), CC - 1);
        c1 = min(max(c1, 0), CC - 1);
        float v0 = xr[tl][c0], v1 = xr[tl][c1];
        out[(size_t)which * OUT_HALF + ((size_t)(b * TT_) + t0 + tl) * KK + k] =
            v0 * (1.0f - w1) + v1 * w1;
    }
}

extern "C" void kernel_launch(void* const* d_in, const int* in_sizes, int n_in,
                              void* d_out, int out_size, void* d_ws, size_t ws_size,
                              hipStream_t stream) {
    const float* x_in   = (const float*)d_in[0];
    const float* W_dim  = (const float*)d_in[1];
    const float* b_dim  = (const float*)d_in[2];
    const float* W_time = (const float*)d_in[3];
    const float* b_time = (const float*)d_in[4];
    const float* W_offa = (const float*)d_in[5];
    const float* W_offd = (const float*)d_in[6];
    float* out = (float*)d_out;
    float* ws  = (float*)d_ws;

    // ws layout (float units):
    unsigned short* att_b = (unsigned short*)ws;   // 16*153664 bf16 = 1,229,312 fl
    float*          xi    = ws + 1229312;          // 6272*64 fp32   =   401,408 fl
    float*          xt    = ws + 1630720;          //     6,272 fl (fp32, zeroed by k_xi)
    float*          wix   = ws + 1636992;          //     6,272 fl
    // total ~6.6 MB

    k_xi<<<98, 256, 0, stream>>>(x_in, W_dim, b_dim, xi, xt);
    k_att<<<dim3(BB, 7), 256, 0, stream>>>(xi, att_b);
    k_xt<<<dim3(NC2, NJT), 128, 0, stream>>>(W_time, att_b, xt);
    k_off<<<25, 256, 0, stream>>>(xt, b_time, W_offa, W_offd, wix);
    k_sample<<<dim3(BB, TT_ / 4), 256, 0, stream>>>(x_in, wix, out);
}